// Round 6
// baseline (63.114 us; speedup 1.0000x reference)
//
#include <hip/hip_runtime.h>

// HistogramEqualization: reference collapses to out = x * h1/(N - h0), where
// h0 = #(x < 1/256), h1 = #(1/256 <= x < 2/256). (jnp.interp over [0,1] only
// uses cdfn[0..1], and cdfn[0]==0 since cdf.min()==cdf[0].)
//
// R6: abandoned register-resident fusion (payload = 78% of the whole VGPR
// file -> remat (R4) or spill (R5)). Two-pass, but EXACT-COVER unrolls:
// grid 4096 x 256 x 6 float4 == n4 exactly -> no 1-deep remainder loop, no
// grid-stride overhead, full occupancy (24 payload VGPRs, launch_bounds(256,8)).
// Count via two float compares (cA = #(x<1/256), cB = #(x<2/256); h1 = cB-cA).

#define TBLK 256
#define EC_CHUNK 6  // float4 per thread on the exact path

__global__ __launch_bounds__(TBLK, 8) void histeq_count_exact(
    const float4* __restrict__ x4, unsigned long long* __restrict__ partials) {
    const int total = gridDim.x * TBLK;
    const int tid = blockIdx.x * TBLK + threadIdx.x;

    float4 v[EC_CHUNK];
#pragma unroll
    for (int k = 0; k < EC_CHUNK; ++k) v[k] = x4[tid + k * total];

    const float T1 = 0.00390625f;  // 1/256
    const float T2 = 0.0078125f;   // 2/256
    unsigned int cA = 0, cB = 0;
#pragma unroll
    for (int k = 0; k < EC_CHUNK; ++k) {
        cA += (v[k].x < T1) ? 1u : 0u;
        cA += (v[k].y < T1) ? 1u : 0u;
        cA += (v[k].z < T1) ? 1u : 0u;
        cA += (v[k].w < T1) ? 1u : 0u;
        cB += (v[k].x < T2) ? 1u : 0u;
        cB += (v[k].y < T2) ? 1u : 0u;
        cB += (v[k].z < T2) ? 1u : 0u;
        cB += (v[k].w < T2) ? 1u : 0u;
    }
#pragma unroll
    for (int off = 32; off > 0; off >>= 1) {
        cA += __shfl_down(cA, off, 64);
        cB += __shfl_down(cB, off, 64);
    }
    __shared__ unsigned int smA[4], smB[4];
    const int lane = threadIdx.x & 63;
    const int wid = threadIdx.x >> 6;
    if (lane == 0) { smA[wid] = cA; smB[wid] = cB; }
    __syncthreads();
    if (threadIdx.x == 0) {
        unsigned long long tA = smA[0] + smA[1] + smA[2] + smA[3];
        unsigned long long tB = smB[0] + smB[1] + smB[2] + smB[3];
        partials[blockIdx.x] = tA | (tB << 32);  // plain store, no init needed
    }
}

__global__ __launch_bounds__(TBLK, 8) void histeq_apply_exact(
    const float4* __restrict__ x4, float4* __restrict__ out4,
    const unsigned long long* __restrict__ partials, int nparts, int n_total) {
    // reduce per-block partials (nparts<=4096, L2-resident)
    unsigned int cA = 0, cB = 0;
    for (int j = threadIdx.x; j < nparts; j += TBLK) {
        unsigned long long p = partials[j];
        cA += (unsigned int)(p & 0xFFFFFFFFull);
        cB += (unsigned int)(p >> 32);
    }
#pragma unroll
    for (int off = 32; off > 0; off >>= 1) {
        cA += __shfl_down(cA, off, 64);
        cB += __shfl_down(cB, off, 64);
    }
    __shared__ unsigned int smA[4], smB[4];
    __shared__ float s_scale;
    const int lane = threadIdx.x & 63;
    const int wid = threadIdx.x >> 6;
    if (lane == 0) { smA[wid] = cA; smB[wid] = cB; }
    __syncthreads();
    if (threadIdx.x == 0) {
        double h0 = (double)(smA[0] + smA[1] + smA[2] + smA[3]);
        double hB = (double)(smB[0] + smB[1] + smB[2] + smB[3]);
        double h1 = hB - h0;
        s_scale = (float)(h1 / ((double)n_total - h0));
    }
    __syncthreads();
    const float s = s_scale;

    const int total = gridDim.x * TBLK;
    const int tid = blockIdx.x * TBLK + threadIdx.x;

    float4 v[EC_CHUNK];
#pragma unroll
    for (int k = 0; k < EC_CHUNK; ++k) v[k] = x4[tid + k * total];
#pragma unroll
    for (int k = 0; k < EC_CHUNK; ++k) {
        float4 o;
        o.x = v[k].x * s;
        o.y = v[k].y * s;
        o.z = v[k].z * s;
        o.w = v[k].w * s;
        out4[tid + k * total] = o;
    }
}

// ---------------- fallback path (generic n) ----------------

__global__ __launch_bounds__(256) void histeq_count(const float4* __restrict__ x4,
                                                    unsigned long long* __restrict__ partials,
                                                    int n4, const float* __restrict__ x,
                                                    int n) {
    const float T1 = 0.00390625f, T2 = 0.0078125f;
    unsigned int cA = 0, cB = 0;
    const int tid = blockIdx.x * blockDim.x + threadIdx.x;
    const int stride = gridDim.x * blockDim.x;

    int i = tid;
    for (; i + 7 * stride < n4; i += 8 * stride) {
        float4 v[8];
#pragma unroll
        for (int k = 0; k < 8; ++k) v[k] = x4[i + k * stride];
#pragma unroll
        for (int k = 0; k < 8; ++k) {
            cA += (v[k].x < T1) + (v[k].y < T1) + (v[k].z < T1) + (v[k].w < T1);
            cB += (v[k].x < T2) + (v[k].y < T2) + (v[k].z < T2) + (v[k].w < T2);
        }
    }
    for (; i < n4; i += stride) {
        float4 v = x4[i];
        cA += (v.x < T1) + (v.y < T1) + (v.z < T1) + (v.w < T1);
        cB += (v.x < T2) + (v.y < T2) + (v.z < T2) + (v.w < T2);
    }
    if (blockIdx.x == 0 && threadIdx.x == 0) {
        for (int j = n4 * 4; j < n; ++j) {
            float f = x[j];
            cA += (f < T1);
            cB += (f < T2);
        }
    }
#pragma unroll
    for (int off = 32; off > 0; off >>= 1) {
        cA += __shfl_down(cA, off, 64);
        cB += __shfl_down(cB, off, 64);
    }
    __shared__ unsigned int smA[4], smB[4];
    int lane = threadIdx.x & 63;
    int wid = threadIdx.x >> 6;
    if (lane == 0) { smA[wid] = cA; smB[wid] = cB; }
    __syncthreads();
    if (threadIdx.x == 0) {
        unsigned long long tA = smA[0] + smA[1] + smA[2] + smA[3];
        unsigned long long tB = smB[0] + smB[1] + smB[2] + smB[3];
        partials[blockIdx.x] = tA | (tB << 32);
    }
}

__global__ __launch_bounds__(256) void histeq_apply(const float4* __restrict__ x4,
                                                    float4* __restrict__ out4,
                                                    const unsigned long long* __restrict__ partials,
                                                    int nparts,
                                                    int n4, int n_total,
                                                    const float* __restrict__ x,
                                                    float* __restrict__ out) {
    unsigned int cA = 0, cB = 0;
    for (int j = threadIdx.x; j < nparts; j += blockDim.x) {
        unsigned long long p = partials[j];
        cA += (unsigned int)(p & 0xFFFFFFFFull);
        cB += (unsigned int)(p >> 32);
    }
#pragma unroll
    for (int off = 32; off > 0; off >>= 1) {
        cA += __shfl_down(cA, off, 64);
        cB += __shfl_down(cB, off, 64);
    }
    __shared__ unsigned int smA[4], smB[4];
    __shared__ float s_scale;
    int lane = threadIdx.x & 63;
    int wid = threadIdx.x >> 6;
    if (lane == 0) { smA[wid] = cA; smB[wid] = cB; }
    __syncthreads();
    if (threadIdx.x == 0) {
        double h0 = (double)(smA[0] + smA[1] + smA[2] + smA[3]);
        double hB = (double)(smB[0] + smB[1] + smB[2] + smB[3]);
        s_scale = (float)((hB - h0) / ((double)n_total - h0));
    }
    __syncthreads();
    const float s = s_scale;
    const int tid = blockIdx.x * blockDim.x + threadIdx.x;
    const int stride = gridDim.x * blockDim.x;

    int i = tid;
    for (; i + 7 * stride < n4; i += 8 * stride) {
        float4 v[8];
#pragma unroll
        for (int k = 0; k < 8; ++k) v[k] = x4[i + k * stride];
#pragma unroll
        for (int k = 0; k < 8; ++k) {
            float4 o;
            o.x = v[k].x * s;
            o.y = v[k].y * s;
            o.z = v[k].z * s;
            o.w = v[k].w * s;
            out4[i + k * stride] = o;
        }
    }
    for (; i < n4; i += stride) {
        float4 v = x4[i];
        float4 o;
        o.x = v.x * s;
        o.y = v.y * s;
        o.z = v.z * s;
        o.w = v.w * s;
        out4[i] = o;
    }
    if (blockIdx.x == 0 && threadIdx.x == 0) {
        for (int j = n4 * 4; j < n_total; ++j) out[j] = x[j] * s;
    }
}

extern "C" void kernel_launch(void* const* d_in, const int* in_sizes, int n_in,
                              void* d_out, int out_size, void* d_ws, size_t ws_size,
                              hipStream_t stream) {
    const float* x = (const float*)d_in[0];
    float* out = (float*)d_out;
    int n = in_sizes[0];
    int n4 = n >> 2;
    unsigned long long* partials = (unsigned long long*)d_ws;

    const int per = TBLK * EC_CHUNK;  // elements (float4) covered per block
    bool exact = (n == n4 * 4) && (n4 % per == 0);
    int G = exact ? (n4 / per) : 0;
    exact = exact && G >= 1 && G <= 8192 &&
            ws_size >= (size_t)G * sizeof(unsigned long long);

    if (exact) {
        histeq_count_exact<<<G, TBLK, 0, stream>>>((const float4*)x, partials);
        histeq_apply_exact<<<G, TBLK, 0, stream>>>((const float4*)x, (float4*)out,
                                                   partials, G, n);
        return;
    }

    const int block = 256;
    int grid = 2048;
    int need = (n4 + block - 1) / block;
    if (grid > need) grid = need;
    if (grid < 1) grid = 1;

    histeq_count<<<grid, block, 0, stream>>>((const float4*)x, partials, n4, x, n);
    histeq_apply<<<grid, block, 0, stream>>>((const float4*)x, (float4*)out, partials,
                                             grid, n4, n, x, out);
}

// Round 7
// 57.882 us; speedup vs baseline: 1.0904x; 1.0904x over previous
//
#include <hip/hip_runtime.h>

// HistogramEqualization: reference collapses to out = x * h1/(N - h0), where
// h0 = #(x < 1/256), h1 = #(1/256 <= x < 2/256). (jnp.interp over [0,1] only
// uses cdfn[0..1], and cdfn[0]==0 since cdf.min()==cdf[0].)
//
// R7: back to R3's winning shape (grid 2048), but exact-cover:
// n4 = 6291456 = 2048*256*12, so each thread owns exactly 12 float4 -> one
// 12-deep load batch, no remainder loop. Apply issues its 12 payload loads
// BEFORE the partials reduce (overlap), and uses NON-TEMPORAL stores so the
// 100MB output never evicts the input from the 256MB Infinity Cache.

typedef float f32x4 __attribute__((ext_vector_type(4)));

#define TBLK 256
#define ECHUNK 12
#define EGRID 2048  // EGRID*TBLK*ECHUNK == n4 for n = 32*3*512*512

__global__ __launch_bounds__(TBLK, 6) void histeq_count_exact(
    const f32x4* __restrict__ x4, unsigned long long* __restrict__ partials) {
    const int total = EGRID * TBLK;
    const int tid = blockIdx.x * TBLK + threadIdx.x;

    f32x4 v[ECHUNK];
#pragma unroll
    for (int k = 0; k < ECHUNK; ++k) v[k] = x4[tid + k * total];

    const float T1 = 0.00390625f;  // 1/256
    const float T2 = 0.0078125f;   // 2/256
    unsigned int cA = 0, cB = 0;
#pragma unroll
    for (int k = 0; k < ECHUNK; ++k) {
        cA += (v[k].x < T1) + (v[k].y < T1) + (v[k].z < T1) + (v[k].w < T1);
        cB += (v[k].x < T2) + (v[k].y < T2) + (v[k].z < T2) + (v[k].w < T2);
    }
#pragma unroll
    for (int off = 32; off > 0; off >>= 1) {
        cA += __shfl_down(cA, off, 64);
        cB += __shfl_down(cB, off, 64);
    }
    __shared__ unsigned int smA[4], smB[4];
    const int lane = threadIdx.x & 63;
    const int wid = threadIdx.x >> 6;
    if (lane == 0) { smA[wid] = cA; smB[wid] = cB; }
    __syncthreads();
    if (threadIdx.x == 0) {
        unsigned long long tA = smA[0] + smA[1] + smA[2] + smA[3];
        unsigned long long tB = smB[0] + smB[1] + smB[2] + smB[3];
        partials[blockIdx.x] = tA | (tB << 32);  // plain store, no init needed
    }
}

__global__ __launch_bounds__(TBLK, 6) void histeq_apply_exact(
    const f32x4* __restrict__ x4, f32x4* __restrict__ out4,
    const unsigned long long* __restrict__ partials, int n_total) {
    const int total = EGRID * TBLK;
    const int tid = blockIdx.x * TBLK + threadIdx.x;

    // Issue payload loads first; the partials reduce below overlaps their flight.
    f32x4 v[ECHUNK];
#pragma unroll
    for (int k = 0; k < ECHUNK; ++k) v[k] = x4[tid + k * total];

    unsigned int cA = 0, cB = 0;
#pragma unroll
    for (int j = 0; j < EGRID / TBLK; ++j) {
        unsigned long long p = partials[threadIdx.x + j * TBLK];
        cA += (unsigned int)(p & 0xFFFFFFFFull);
        cB += (unsigned int)(p >> 32);
    }
#pragma unroll
    for (int off = 32; off > 0; off >>= 1) {
        cA += __shfl_down(cA, off, 64);
        cB += __shfl_down(cB, off, 64);
    }
    __shared__ unsigned int smA[4], smB[4];
    __shared__ float s_scale;
    const int lane = threadIdx.x & 63;
    const int wid = threadIdx.x >> 6;
    if (lane == 0) { smA[wid] = cA; smB[wid] = cB; }
    __syncthreads();
    if (threadIdx.x == 0) {
        double h0 = (double)(smA[0] + smA[1] + smA[2] + smA[3]);
        double hB = (double)(smB[0] + smB[1] + smB[2] + smB[3]);
        s_scale = (float)((hB - h0) / ((double)n_total - h0));
    }
    __syncthreads();
    const float s = s_scale;

#pragma unroll
    for (int k = 0; k < ECHUNK; ++k) {
        f32x4 o = v[k] * s;
        // NT store: don't allocate output in L2/L3 -> input stays cache-resident.
        __builtin_nontemporal_store(o, &out4[tid + k * total]);
    }
}

// ---------------- fallback path (generic n) ----------------

__global__ __launch_bounds__(256) void histeq_count(const float4* __restrict__ x4,
                                                    unsigned long long* __restrict__ partials,
                                                    int n4, const float* __restrict__ x,
                                                    int n) {
    const float T1 = 0.00390625f, T2 = 0.0078125f;
    unsigned int cA = 0, cB = 0;
    const int tid = blockIdx.x * blockDim.x + threadIdx.x;
    const int stride = gridDim.x * blockDim.x;

    int i = tid;
    for (; i + 7 * stride < n4; i += 8 * stride) {
        float4 v[8];
#pragma unroll
        for (int k = 0; k < 8; ++k) v[k] = x4[i + k * stride];
#pragma unroll
        for (int k = 0; k < 8; ++k) {
            cA += (v[k].x < T1) + (v[k].y < T1) + (v[k].z < T1) + (v[k].w < T1);
            cB += (v[k].x < T2) + (v[k].y < T2) + (v[k].z < T2) + (v[k].w < T2);
        }
    }
    for (; i < n4; i += stride) {
        float4 v = x4[i];
        cA += (v.x < T1) + (v.y < T1) + (v.z < T1) + (v.w < T1);
        cB += (v.x < T2) + (v.y < T2) + (v.z < T2) + (v.w < T2);
    }
    if (blockIdx.x == 0 && threadIdx.x == 0) {
        for (int j = n4 * 4; j < n; ++j) {
            float f = x[j];
            cA += (f < T1);
            cB += (f < T2);
        }
    }
#pragma unroll
    for (int off = 32; off > 0; off >>= 1) {
        cA += __shfl_down(cA, off, 64);
        cB += __shfl_down(cB, off, 64);
    }
    __shared__ unsigned int smA[4], smB[4];
    int lane = threadIdx.x & 63;
    int wid = threadIdx.x >> 6;
    if (lane == 0) { smA[wid] = cA; smB[wid] = cB; }
    __syncthreads();
    if (threadIdx.x == 0) {
        unsigned long long tA = smA[0] + smA[1] + smA[2] + smA[3];
        unsigned long long tB = smB[0] + smB[1] + smB[2] + smB[3];
        partials[blockIdx.x] = tA | (tB << 32);
    }
}

__global__ __launch_bounds__(256) void histeq_apply(const float4* __restrict__ x4,
                                                    float4* __restrict__ out4,
                                                    const unsigned long long* __restrict__ partials,
                                                    int nparts,
                                                    int n4, int n_total,
                                                    const float* __restrict__ x,
                                                    float* __restrict__ out) {
    unsigned int cA = 0, cB = 0;
    for (int j = threadIdx.x; j < nparts; j += blockDim.x) {
        unsigned long long p = partials[j];
        cA += (unsigned int)(p & 0xFFFFFFFFull);
        cB += (unsigned int)(p >> 32);
    }
#pragma unroll
    for (int off = 32; off > 0; off >>= 1) {
        cA += __shfl_down(cA, off, 64);
        cB += __shfl_down(cB, off, 64);
    }
    __shared__ unsigned int smA[4], smB[4];
    __shared__ float s_scale;
    int lane = threadIdx.x & 63;
    int wid = threadIdx.x >> 6;
    if (lane == 0) { smA[wid] = cA; smB[wid] = cB; }
    __syncthreads();
    if (threadIdx.x == 0) {
        double h0 = (double)(smA[0] + smA[1] + smA[2] + smA[3]);
        double hB = (double)(smB[0] + smB[1] + smB[2] + smB[3]);
        s_scale = (float)((hB - h0) / ((double)n_total - h0));
    }
    __syncthreads();
    const float s = s_scale;
    const int tid = blockIdx.x * blockDim.x + threadIdx.x;
    const int stride = gridDim.x * blockDim.x;

    int i = tid;
    for (; i + 7 * stride < n4; i += 8 * stride) {
        float4 v[8];
#pragma unroll
        for (int k = 0; k < 8; ++k) v[k] = x4[i + k * stride];
#pragma unroll
        for (int k = 0; k < 8; ++k) {
            float4 o;
            o.x = v[k].x * s;
            o.y = v[k].y * s;
            o.z = v[k].z * s;
            o.w = v[k].w * s;
            out4[i + k * stride] = o;
        }
    }
    for (; i < n4; i += stride) {
        float4 v = x4[i];
        float4 o;
        o.x = v.x * s;
        o.y = v.y * s;
        o.z = v.z * s;
        o.w = v.w * s;
        out4[i] = o;
    }
    if (blockIdx.x == 0 && threadIdx.x == 0) {
        for (int j = n4 * 4; j < n_total; ++j) out[j] = x[j] * s;
    }
}

extern "C" void kernel_launch(void* const* d_in, const int* in_sizes, int n_in,
                              void* d_out, int out_size, void* d_ws, size_t ws_size,
                              hipStream_t stream) {
    const float* x = (const float*)d_in[0];
    float* out = (float*)d_out;
    int n = in_sizes[0];
    int n4 = n >> 2;
    unsigned long long* partials = (unsigned long long*)d_ws;

    bool exact = (n == n4 * 4) && (n4 == EGRID * TBLK * ECHUNK) &&
                 (ws_size >= (size_t)EGRID * sizeof(unsigned long long));
    if (exact) {
        histeq_count_exact<<<EGRID, TBLK, 0, stream>>>((const f32x4*)x, partials);
        histeq_apply_exact<<<EGRID, TBLK, 0, stream>>>((const f32x4*)x, (f32x4*)out,
                                                       partials, n);
        return;
    }

    const int block = 256;
    int grid = 2048;
    int need = (n4 + block - 1) / block;
    if (grid > need) grid = need;
    if (grid < 1) grid = 1;

    histeq_count<<<grid, block, 0, stream>>>((const float4*)x, partials, n4, x, n);
    histeq_apply<<<grid, block, 0, stream>>>((const float4*)x, (float4*)out, partials,
                                             grid, n4, n, x, out);
}

// Round 8
// 53.212 us; speedup vs baseline: 1.1861x; 1.0878x over previous
//
#include <hip/hip_runtime.h>

// HistogramEqualization: reference collapses to out = x * h1/(N - h0), where
// h0 = #(x < 1/256), h1 = #(1/256 <= x < 2/256). (jnp.interp over [0,1] only
// uses cdfn[0..1], and cdfn[0]==0 since cdf.min()==cdf[0].)
//
// R8: occupancy fix. launch_bounds(256,8) -> VGPR cap 64 -> 8 waves/SIMD ->
// 8 blocks/CU -> all 2048 blocks co-resident (one clean round, no ragged
// tail). Count consumes in 3x4 batches (compiler pipelines under the cap).
// Apply issues partials loads FIRST (vmcnt is issue-ordered: s-reduce then
// overlaps payload flight), double-buffers payload 4-deep, NT stores.

typedef float f32x4 __attribute__((ext_vector_type(4)));

#define TBLK 256
#define ECHUNK 12
#define EGRID 2048  // EGRID*TBLK*ECHUNK == n4 for n = 32*3*512*512
#define NPART (EGRID / TBLK)  // partials loads per thread in apply

__global__ __launch_bounds__(TBLK, 8) void histeq_count_exact(
    const f32x4* __restrict__ x4, unsigned long long* __restrict__ partials) {
    const int total = EGRID * TBLK;
    const int tid = blockIdx.x * TBLK + threadIdx.x;

    const float T1 = 0.00390625f;  // 1/256
    const float T2 = 0.0078125f;   // 2/256
    unsigned int cA = 0, cB = 0;

#pragma unroll
    for (int b = 0; b < ECHUNK / 4; ++b) {
        f32x4 v[4];
#pragma unroll
        for (int k = 0; k < 4; ++k) v[k] = x4[tid + (b * 4 + k) * total];
#pragma unroll
        for (int k = 0; k < 4; ++k) {
            cA += (v[k].x < T1) + (v[k].y < T1) + (v[k].z < T1) + (v[k].w < T1);
            cB += (v[k].x < T2) + (v[k].y < T2) + (v[k].z < T2) + (v[k].w < T2);
        }
    }
#pragma unroll
    for (int off = 32; off > 0; off >>= 1) {
        cA += __shfl_down(cA, off, 64);
        cB += __shfl_down(cB, off, 64);
    }
    __shared__ unsigned int smA[4], smB[4];
    const int lane = threadIdx.x & 63;
    const int wid = threadIdx.x >> 6;
    if (lane == 0) { smA[wid] = cA; smB[wid] = cB; }
    __syncthreads();
    if (threadIdx.x == 0) {
        unsigned long long tA = smA[0] + smA[1] + smA[2] + smA[3];
        unsigned long long tB = smB[0] + smB[1] + smB[2] + smB[3];
        partials[blockIdx.x] = tA | (tB << 32);  // plain store, no init needed
    }
}

__global__ __launch_bounds__(TBLK, 8) void histeq_apply_exact(
    const f32x4* __restrict__ x4, f32x4* __restrict__ out4,
    const unsigned long long* __restrict__ partials, int n_total) {
    const int total = EGRID * TBLK;
    const int tid = blockIdx.x * TBLK + threadIdx.x;

    // 1) partials loads issued FIRST (oldest in vmcnt order)
    unsigned long long p[NPART];
#pragma unroll
    for (int j = 0; j < NPART; ++j) p[j] = partials[threadIdx.x + j * TBLK];

    // 2) first payload batch in flight behind them
    f32x4 v[4];
#pragma unroll
    for (int k = 0; k < 4; ++k) v[k] = x4[tid + k * total];

    // 3) consume partials (waits only for the oldest loads), compute s
    unsigned int cA = 0, cB = 0;
#pragma unroll
    for (int j = 0; j < NPART; ++j) {
        cA += (unsigned int)(p[j] & 0xFFFFFFFFull);
        cB += (unsigned int)(p[j] >> 32);
    }
#pragma unroll
    for (int off = 32; off > 0; off >>= 1) {
        cA += __shfl_down(cA, off, 64);
        cB += __shfl_down(cB, off, 64);
    }
    __shared__ unsigned int smA[4], smB[4];
    __shared__ float s_scale;
    const int lane = threadIdx.x & 63;
    const int wid = threadIdx.x >> 6;
    if (lane == 0) { smA[wid] = cA; smB[wid] = cB; }
    __syncthreads();
    if (threadIdx.x == 0) {
        double h0 = (double)(smA[0] + smA[1] + smA[2] + smA[3]);
        double hB = (double)(smB[0] + smB[1] + smB[2] + smB[3]);
        s_scale = (float)((hB - h0) / ((double)n_total - h0));
    }
    __syncthreads();
    const float s = s_scale;

    // 4) double-buffered batches: prefetch next while storing current (NT)
#pragma unroll
    for (int b = 0; b < ECHUNK / 4; ++b) {
        f32x4 w[4];
        if (b + 1 < ECHUNK / 4) {
#pragma unroll
            for (int k = 0; k < 4; ++k) w[k] = x4[tid + ((b + 1) * 4 + k) * total];
        }
#pragma unroll
        for (int k = 0; k < 4; ++k) {
            f32x4 o = v[k] * s;
            __builtin_nontemporal_store(o, &out4[tid + (b * 4 + k) * total]);
        }
        if (b + 1 < ECHUNK / 4) {
#pragma unroll
            for (int k = 0; k < 4; ++k) v[k] = w[k];
        }
    }
}

// ---------------- fallback path (generic n) ----------------

__global__ __launch_bounds__(256) void histeq_count(const float4* __restrict__ x4,
                                                    unsigned long long* __restrict__ partials,
                                                    int n4, const float* __restrict__ x,
                                                    int n) {
    const float T1 = 0.00390625f, T2 = 0.0078125f;
    unsigned int cA = 0, cB = 0;
    const int tid = blockIdx.x * blockDim.x + threadIdx.x;
    const int stride = gridDim.x * blockDim.x;

    int i = tid;
    for (; i + 7 * stride < n4; i += 8 * stride) {
        float4 v[8];
#pragma unroll
        for (int k = 0; k < 8; ++k) v[k] = x4[i + k * stride];
#pragma unroll
        for (int k = 0; k < 8; ++k) {
            cA += (v[k].x < T1) + (v[k].y < T1) + (v[k].z < T1) + (v[k].w < T1);
            cB += (v[k].x < T2) + (v[k].y < T2) + (v[k].z < T2) + (v[k].w < T2);
        }
    }
    for (; i < n4; i += stride) {
        float4 v = x4[i];
        cA += (v.x < T1) + (v.y < T1) + (v.z < T1) + (v.w < T1);
        cB += (v.x < T2) + (v.y < T2) + (v.z < T2) + (v.w < T2);
    }
    if (blockIdx.x == 0 && threadIdx.x == 0) {
        for (int j = n4 * 4; j < n; ++j) {
            float f = x[j];
            cA += (f < T1);
            cB += (f < T2);
        }
    }
#pragma unroll
    for (int off = 32; off > 0; off >>= 1) {
        cA += __shfl_down(cA, off, 64);
        cB += __shfl_down(cB, off, 64);
    }
    __shared__ unsigned int smA[4], smB[4];
    int lane = threadIdx.x & 63;
    int wid = threadIdx.x >> 6;
    if (lane == 0) { smA[wid] = cA; smB[wid] = cB; }
    __syncthreads();
    if (threadIdx.x == 0) {
        unsigned long long tA = smA[0] + smA[1] + smA[2] + smA[3];
        unsigned long long tB = smB[0] + smB[1] + smB[2] + smB[3];
        partials[blockIdx.x] = tA | (tB << 32);
    }
}

__global__ __launch_bounds__(256) void histeq_apply(const float4* __restrict__ x4,
                                                    float4* __restrict__ out4,
                                                    const unsigned long long* __restrict__ partials,
                                                    int nparts,
                                                    int n4, int n_total,
                                                    const float* __restrict__ x,
                                                    float* __restrict__ out) {
    unsigned int cA = 0, cB = 0;
    for (int j = threadIdx.x; j < nparts; j += blockDim.x) {
        unsigned long long p = partials[j];
        cA += (unsigned int)(p & 0xFFFFFFFFull);
        cB += (unsigned int)(p >> 32);
    }
#pragma unroll
    for (int off = 32; off > 0; off >>= 1) {
        cA += __shfl_down(cA, off, 64);
        cB += __shfl_down(cB, off, 64);
    }
    __shared__ unsigned int smA[4], smB[4];
    __shared__ float s_scale;
    int lane = threadIdx.x & 63;
    int wid = threadIdx.x >> 6;
    if (lane == 0) { smA[wid] = cA; smB[wid] = cB; }
    __syncthreads();
    if (threadIdx.x == 0) {
        double h0 = (double)(smA[0] + smA[1] + smA[2] + smA[3]);
        double hB = (double)(smB[0] + smB[1] + smB[2] + smB[3]);
        s_scale = (float)((hB - h0) / ((double)n_total - h0));
    }
    __syncthreads();
    const float s = s_scale;
    const int tid = blockIdx.x * blockDim.x + threadIdx.x;
    const int stride = gridDim.x * blockDim.x;

    int i = tid;
    for (; i + 7 * stride < n4; i += 8 * stride) {
        float4 v[8];
#pragma unroll
        for (int k = 0; k < 8; ++k) v[k] = x4[i + k * stride];
#pragma unroll
        for (int k = 0; k < 8; ++k) {
            float4 o;
            o.x = v[k].x * s;
            o.y = v[k].y * s;
            o.z = v[k].z * s;
            o.w = v[k].w * s;
            out4[i + k * stride] = o;
        }
    }
    for (; i < n4; i += stride) {
        float4 v = x4[i];
        float4 o;
        o.x = v.x * s;
        o.y = v.y * s;
        o.z = v.z * s;
        o.w = v.w * s;
        out4[i] = o;
    }
    if (blockIdx.x == 0 && threadIdx.x == 0) {
        for (int j = n4 * 4; j < n_total; ++j) out[j] = x[j] * s;
    }
}

extern "C" void kernel_launch(void* const* d_in, const int* in_sizes, int n_in,
                              void* d_out, int out_size, void* d_ws, size_t ws_size,
                              hipStream_t stream) {
    const float* x = (const float*)d_in[0];
    float* out = (float*)d_out;
    int n = in_sizes[0];
    int n4 = n >> 2;
    unsigned long long* partials = (unsigned long long*)d_ws;

    bool exact = (n == n4 * 4) && (n4 == EGRID * TBLK * ECHUNK) &&
                 (ws_size >= (size_t)EGRID * sizeof(unsigned long long));
    if (exact) {
        histeq_count_exact<<<EGRID, TBLK, 0, stream>>>((const f32x4*)x, partials);
        histeq_apply_exact<<<EGRID, TBLK, 0, stream>>>((const f32x4*)x, (f32x4*)out,
                                                       partials, n);
        return;
    }

    const int block = 256;
    int grid = 2048;
    int need = (n4 + block - 1) / block;
    if (grid > need) grid = need;
    if (grid < 1) grid = 1;

    histeq_count<<<grid, block, 0, stream>>>((const float4*)x, partials, n4, x, n);
    histeq_apply<<<grid, block, 0, stream>>>((const float4*)x, (float4*)out, partials,
                                             grid, n4, n, x, out);
}